// Round 17
// baseline (230.690 us; speedup 1.0000x reference)
//
#include <hip/hip_runtime.h>

#define NA      30000
#define MPAD    30080            // 235 * 128
#define NPAIRS  1200000
#define NB      7
#define NK      5
#define NSP     119
#define NFEAT   360
#define KP1     384              // NFEAT padded to 64
#define NU      512
#define WROWH   40               // padded W row: 5 k-groups x 8 halfs (80B, 16B aligned)
#define MAXSLOT 120              // slots per atom (Poisson(40): P(deg>120) ~ 0)
#define LPSTR   136              // lp row stride in ints (R17: ≡8 mod 32 -> exact 2-way)
#define NBKF    235              // fine buckets of 128 atoms
#define BCAPF   5760             // entries per fine bucket (mean 5120, sd ~71; +9sigma)
#define PPB     4688             // pairs per partition block (256 blocks)
#define NTILE   235              // 128-atom tiles

#define BETTA      1.3611111111111112f     // 49/36
#define RADNORM    0.96481348f             // (2*betta/pi)^0.25
#define SHIFT_STEP 0.7857142857142857f     // 5.5/7
#define PI_OVER_R  0.5235987755982988f     // pi/6
#define INV_SQRT7  0.3779644730092272f
#define RMAXV      6.0f
#define TCOEF      2.138888888888889f      // 2*betta*h, h = 5.5/7

typedef __attribute__((ext_vector_type(8))) short bf16x8;
typedef __attribute__((ext_vector_type(4))) float f32x4;
typedef __attribute__((ext_vector_type(2))) float f32x2;
typedef __attribute__((ext_vector_type(4))) unsigned int u32x4;
typedef _Float16 h16x2 __attribute__((ext_vector_type(2)));

__device__ __forceinline__ unsigned short f2b(float x) {
    unsigned u = __float_as_uint(x);
    unsigned r = u + 0x7FFF + ((u >> 16) & 1);   // RNE (inputs are finite)
    return (unsigned short)(r >> 16);
}

// ---------------- phase 1: partition pairs into 235 fine buckets -----------------
// entry pack: (i&127)<<22 | Zj<<15 | j   (iloc 7b, Zj 7b, j 15b)
__global__ __launch_bounds__(256)
void k_part(const int* __restrict__ idx, const int* __restrict__ Z,
            int* __restrict__ gcur, int* __restrict__ part) {
    __shared__ int hist[NBKF];
    __shared__ int base[NBKF];
    int tid = threadIdx.x;
    for (int b = tid; b < NBKF; b += 256) hist[b] = 0;
    __syncthreads();
    int p0 = blockIdx.x * PPB;
    int p1 = min(p0 + PPB, NPAIRS);
    for (int p = p0 + tid; p < p1; p += 256)
        atomicAdd(&hist[idx[p] >> 7], 1);
    __syncthreads();
    for (int b = tid; b < NBKF; b += 256) {
        base[b] = atomicAdd(&gcur[b], hist[b]);
        hist[b] = 0;
    }
    __syncthreads();
    for (int p = p0 + tid; p < p1; p += 256) {
        int i = idx[p];
        int b = i >> 7;
        int j = idx[NPAIRS + p];
        int zj = Z[j];
        int off = base[b] + atomicAdd(&hist[b], 1);
        if (off < BCAPF)
            part[b * BCAPF + off] = ((i & 127) << 22) | (zj << 15) | j;
    }
}

// ------- merged prep (runs FIRST): zero gcur + d_out, pad W(fp16 k-major)/R ------
#define PREP_W   (NSP*NSP*WROWH)         // 566440 (fp16 elements)
#define PREP_R   NA                      // 30000
#define PREP_W1  (NU*KP1)                // 196608
#define PREP_W2  (NU*NU)                 // 262144
#define PREP_TOT (PREP_W + PREP_R + PREP_W1 + PREP_W2)
__global__ void k_prep(const float* __restrict__ W, const float* __restrict__ R,
                       const float* __restrict__ w1, const float* __restrict__ w2,
                       unsigned short* __restrict__ Wp, float* __restrict__ Rp,
                       unsigned short* __restrict__ w1T, unsigned short* __restrict__ w2T,
                       int* __restrict__ gcur, float* __restrict__ out) {
    int i = blockIdx.x * blockDim.x + threadIdx.x;
    if (i < 256) gcur[i] = 0;            // 235 fine-bucket cursors (padded)
    if (i < NA) out[i] = 0.f;            // layer-3 accumulator
    if (i < PREP_W) {
        // k-major layout: element e = k*8 + b (b<7 real, b=7 zero pad) -> fdot2 pairs
        int row = i / WROWH, e = i - row * WROWH;
        int k = e >> 3, b = e & 7;
        float v = (b < 7) ? W[row * (NK * NB) + k * NB + b] : 0.f;
        ((_Float16*)Wp)[i] = (_Float16)v;   // RNE f32->f16
        return;
    }
    i -= PREP_W;
    if (i < PREP_R) {
        f32x4 v = {R[3*i], R[3*i+1], R[3*i+2], 0.f};
        *(f32x4*)&Rp[4*i] = v;
        return;
    }
    i -= PREP_R;
    if (i < PREP_W1) {
        int c = i / KP1, kp = i - c * KP1;
        w1T[i] = (kp < NFEAT) ? f2b(w1[kp * NU + c]) : (unsigned short)0;
        return;
    }
    i -= PREP_W1;
    if (i < PREP_W2) {
        int c = i >> 9, kp = i & 511;
        w2T[i] = f2b(w2[kp * NU + c]);
    }
}

// ---------------- phase-B contraction helpers (MS is read via M = MS + lane) -----
#define LDM(comp) M[(comp) * 65]

__device__ __forceinline__ void do_c5(const float* M, unsigned short* STrow,
                                      int r, int s, int foff) {
    const int S2[3][3] = {{0,1,2},{1,3,4},{2,4,5}};
    float m1r[3], m1q[3];
#pragma unroll
    for (int i = 0; i < 3; i++) m1r[i] = LDM(r*20+1+i);
#pragma unroll
    for (int i = 0; i < 3; i++) m1q[i] = LDM(s*20+1+i);
    float pre[9];
#pragma unroll
    for (int i = 0; i < 3; i++)
#pragma unroll
        for (int j = 0; j < 3; j++) pre[i*3+j] = m1r[i] * m1q[j];
    for (int t = 0; t < 5; t++) {
        float m2t[6];
#pragma unroll
        for (int u = 0; u < 6; u++) m2t[u] = LDM(t*20+4+u);
        float v = 0.f;
#pragma unroll
        for (int i = 0; i < 3; i++)
#pragma unroll
            for (int j = 0; j < 3; j++)
                v += pre[i*3+j] * m2t[S2[i][j]];
        STrow[foff + t] = f2b(v);
    }
}

__device__ __forceinline__ void do_c6(const float* M, unsigned short* STrow,
                                      int r, int s, int foff) {
    const int S2[3][3] = {{0,1,2},{1,3,4},{2,4,5}};
    const int S3[3][3][3] = {
        {{0,1,2},{1,3,4},{2,4,5}},
        {{1,3,4},{3,6,7},{4,7,8}},
        {{2,4,5},{4,7,8},{5,8,9}}
    };
    float m3r[10];
#pragma unroll
    for (int u = 0; u < 10; u++) m3r[u] = LDM(r*20+10+u);
    float m2q[6];
#pragma unroll
    for (int u = 0; u < 6; u++) m2q[u] = LDM(s*20+4+u);
    float U0 = 0.f, U1 = 0.f, U2 = 0.f;
#pragma unroll
    for (int i = 0; i < 3; i++)
#pragma unroll
        for (int j = 0; j < 3; j++) {
            float ww = m2q[S2[i][j]];
            U0 += m3r[S3[i][j][0]] * ww;
            U1 += m3r[S3[i][j][1]] * ww;
            U2 += m3r[S3[i][j][2]] * ww;
        }
    for (int t = 0; t < 5; t++) {
        float v = U0 * LDM(t*20+1) + U1 * LDM(t*20+2) + U2 * LDM(t*20+3);
        STrow[foff + t] = f2b(v);
    }
}

__device__ __forceinline__ void do_c7(const float* M, unsigned short* STrow,
                                      int r, int s, int foff) {
    const int S2[3][3] = {{0,1,2},{1,3,4},{2,4,5}};
    const int S3[3][3][3] = {
        {{0,1,2},{1,3,4},{2,4,5}},
        {{1,3,4},{3,6,7},{4,7,8}},
        {{2,4,5},{4,7,8},{5,8,9}}
    };
    float m3r[10], m3q[10];
#pragma unroll
    for (int u = 0; u < 10; u++) m3r[u] = LDM(r*20+10+u);
#pragma unroll
    for (int u = 0; u < 10; u++) m3q[u] = LDM(s*20+10+u);
    float T[3][3];
#pragma unroll
    for (int k = 0; k < 3; k++)
#pragma unroll
        for (int l = 0; l < 3; l++) {
            float v = 0.f;
#pragma unroll
            for (int i = 0; i < 3; i++)
#pragma unroll
                for (int j = 0; j < 3; j++)
                    v += m3r[S3[i][j][k]] * m3q[S3[i][j][l]];
            T[k][l] = v;
        }
    for (int t = 0; t < 5; t++) {
        float m2t[6];
#pragma unroll
        for (int u = 0; u < 6; u++) m2t[u] = LDM(t*20+4+u);
        float v = 0.f;
#pragma unroll
        for (int k = 0; k < 3; k++)
#pragma unroll
            for (int l = 0; l < 3; l++)
                v += T[k][l] * m2t[S2[k][l]];
        STrow[foff + t] = f2b(v);
    }
}

// ------- fused CSR + moments + contraction (R15/R16/R17) -------------------------
// A0: block = 64 atoms = half of fine bucket (blockIdx>>1). Scan bucket from
//   part, keep this half's entries, build rows in LDS lp[64][LPSTR].
//   R17 FIX: stride 136 ints (≡8 mod 32). R16's 129 (≡1) made phase-A read
//   bank = (g+q+8k)%32 — triangular sum, up to 8 lanes/bank (conflicts only
//   dropped 479k->385k). 136: bank = (8*gl+q)%32 — exactly 2 lanes/bank
//   (gl, gl+4), which is free on CDNA4. Capacity 136>=128, masks unchanged.
// Phase A: R5/R8 pair loop, prow read from LDS (lp row).
// Phase B: unchanged (balanced feature split -> ST -> coalesced flushes).
// LDS: MS [0,26000) | lp [26000,60816) (A) / ST [26000,56976) (B) | lc [60816,61072).
//   61072B -> 2 blocks/CU.
__global__ __launch_bounds__(512, 2)
void k_momcon(const float* __restrict__ Rp, const int* __restrict__ Z,
              const unsigned short* __restrict__ WpH, const int* __restrict__ gcnt,
              const int* __restrict__ part, unsigned short* __restrict__ gmB) {
    __shared__ __align__(16) unsigned char LDSM[61072];
    float* MS = (float*)LDSM;                              // [100*65] f32
    int* lp = (int*)(LDSM + 26000);                        // [64][LPSTR] ints (phase A)
    unsigned short* ST = (unsigned short*)(LDSM + 26000);  // [64][242] (phase B)
    int* lc = (int*)(LDSM + 60816);                        // [64]
    int tid = threadIdx.x;
    int a0 = blockIdx.x * 64;

    // ---- A0: build CSR rows for this block's 64 atoms from fine bucket ----
    {
        int bkt = blockIdx.x >> 1;      // fine bucket (128 atoms)
        int half = blockIdx.x & 1;      // which 64-atom half
        for (int t = tid; t < 64; t += 512) lc[t] = 0;
        __syncthreads();
        int n = min(gcnt[bkt], BCAPF);
        for (int e = tid; e < n; e += 512) {
            int v = part[bkt * BCAPF + e];
            int i7 = v >> 22;           // 0..127
            if ((i7 >> 6) == half) {
                int i6 = i7 & 63;
                int r = atomicAdd(&lc[i6], 1);
                if (r < MAXSLOT) lp[i6 * LPSTR + r] = v & 0x3FFFFF;  // Zj<<15 | j
            }
        }
        __syncthreads();
    }

    int g = tid >> 3, q = tid & 7;      // local atom 0..63, lane-in-group
    int a = a0 + g;

    if (a < NA) {
        f32x4 ri = *(const f32x4*)&Rp[4*a];
        int Zi = Z[a];
        f32x2 acc[50];
#pragma unroll
        for (int u = 0; u < 50; u++) acc[u] = (f32x2){0.f, 0.f};
        int cnt = min(lc[g], MAXSLOT);
        const int* prow = lp + g * LPSTR;

        // basis recurrence constants: D[b] = exp(-betah*(1 + h*(2b+1)))
        const float DCH[6] = {0.14812156f, 0.027590652f, 0.0051393300f,
                              0.00095730500f, 0.00017831700f, 3.3215300e-05f};

        // software pipeline: pk two ahead, rj one ahead (clamped garbage-safe)
        int pk0 = prow[q & 127];
        int pk1 = prow[(q + 8) & 127];
        int j0c = min(pk0 & 0x7FFF, NA - 1);
        f32x4 rj = *(const f32x4*)&Rp[4 * j0c];

        for (int t = q; t < cnt; t += 8) {
            int pk2 = prow[(t + 16) & 127];
            int j1c = min(pk1 & 0x7FFF, NA - 1);
            f32x4 rjn = *(const f32x4*)&Rp[4 * j1c];     // prefetch next pair

            int Zj = (pk0 >> 15) & 0x7F;                 // pk0 valid (t < cnt)
            const u32x4* wv = (const u32x4*)(WpH + (size_t)(Zi * NSP + Zj) * WROWH);
            u32x4 wv0 = wv[0], wv1 = wv[1], wv2 = wv[2], wv3 = wv[3], wv4 = wv[4];
            unsigned wu[20];
#pragma unroll
            for (int c = 0; c < 4; c++) {
                wu[c]      = wv0[c];
                wu[4 + c]  = wv1[c];
                wu[8 + c]  = wv2[c];
                wu[12 + c] = wv3[c];
                wu[16 + c] = wv4[c];
            }

            float dx = rj.x - ri.x, dy = rj.y - ri.y, dz = rj.z - ri.z;
            float d2 = dx*dx + dy*dy + dz*dz + 1e-12f;
            float dr = sqrtf(d2);
            float inv = 1.0f / (dr + 1e-5f);
            float nx = dx*inv, ny = dy*inv, nz = dz*inv;

            // basis via recurrence: bb[b+1] = bb[b] * T * D[b]
            float t0 = dr - 0.5f;
            float bb[NB];
            bb[0] = RADNORM * __expf(-BETTA * t0 * t0);
            float Tg = __expf(TCOEF * dr);
#pragma unroll
            for (int b = 0; b < 6; b++) bb[b+1] = bb[b] * Tg * DCH[b];

            float cut = (dr < RMAXV) ? 0.5f * (__cosf(PI_OVER_R * dr) + 1.0f) : 0.0f;
            cut *= INV_SQRT7;

            h16x2 bp[4];
            bp[0] = (h16x2){(_Float16)bb[0], (_Float16)bb[1]};
            bp[1] = (h16x2){(_Float16)bb[2], (_Float16)bb[3]};
            bp[2] = (h16x2){(_Float16)bb[4], (_Float16)bb[5]};
            bp[3] = (h16x2){(_Float16)bb[6], (_Float16)0.0f};

            float rad[NK];
#pragma unroll
            for (int k = 0; k < NK; k++) {
                float s = 0.f;
#if __has_builtin(__builtin_amdgcn_fdot2)
#pragma unroll
                for (int c = 0; c < 4; c++)
                    s = __builtin_amdgcn_fdot2(
                        __builtin_bit_cast(h16x2, wu[k*4 + c]), bp[c], s, false);
#else
#pragma unroll
                for (int c = 0; c < 4; c++) {
                    h16x2 w = __builtin_bit_cast(h16x2, wu[k*4 + c]);
                    s += (float)w.x * (float)bp[c].x + (float)w.y * (float)bp[c].y;
                }
#endif
                rad[k] = s * cut;
            }

            float gg[20];
            gg[0] = 1.f; gg[1] = nx; gg[2] = ny; gg[3] = nz;
            gg[4] = nx*nx; gg[5] = nx*ny; gg[6] = nx*nz; gg[7] = ny*ny; gg[8] = ny*nz; gg[9] = nz*nz;
            gg[10] = gg[4]*nx; gg[11] = gg[4]*ny; gg[12] = gg[4]*nz; gg[13] = gg[5]*ny; gg[14] = gg[5]*nz;
            gg[15] = gg[6]*nz; gg[16] = gg[7]*ny; gg[17] = gg[7]*nz; gg[18] = gg[8]*nz; gg[19] = gg[9]*nz;
            f32x2 g2[10];
#pragma unroll
            for (int u = 0; u < 10; u++) g2[u] = (f32x2){gg[2*u], gg[2*u+1]};
#pragma unroll
            for (int k = 0; k < NK; k++) {
                f32x2 rk = (f32x2){rad[k], rad[k]};
#pragma unroll
                for (int u = 0; u < 10; u++)
                    acc[k*10 + u] += rk * g2[u];      // v_pk_fma_f32
            }
            pk0 = pk1; pk1 = pk2; rj = rjn;
        }
        // reduce within the 8-lane group as 64-bit packets
#pragma unroll
        for (int u = 0; u < 50; u++) {
            f32x2 v = acc[u];
            double d = __builtin_bit_cast(double, v);
            d = __shfl_xor(d, 1);
            v += __builtin_bit_cast(f32x2, d);
            d = __builtin_bit_cast(double, v);
            d = __shfl_xor(d, 2);
            v += __builtin_bit_cast(f32x2, d);
            d = __builtin_bit_cast(double, v);
            d = __shfl_xor(d, 4);
            v += __builtin_bit_cast(f32x2, d);
            acc[u] = v;
        }
        if (q == 0) {
#pragma unroll
            for (int u = 0; u < 50; u++) {
                MS[(2*u)     * 65 + g] = acc[u].x;
                MS[(2*u + 1) * 65 + g] = acc[u].y;
            }
        }
    }
    __syncthreads();                    // phase A done; lp dead, MS ready

    // ---- phase B pass 0: features 0..239 into ST, balanced over 8 waves ----
    int lane = tid & 63, wave = tid >> 6;
    const float* M = MS + lane;
    unsigned short* STrow = ST + lane * 242;

    if (wave == 0) {
        // m0: f0..4
        for (int k = 0; k < 5; k++) STrow[k] = f2b(LDM(k * 20));
        // c1: f5..19
        int f = 5;
        for (int r = 0; r < 5; r++)
            for (int s = r; s < 5; s++) {
                float v = 0.f;
#pragma unroll
                for (int i = 0; i < 3; i++) v += LDM(r*20+1+i) * LDM(s*20+1+i);
                STrow[f++] = f2b(v);
            }
        // c2: f20..34
        const float W2U[6] = {1,2,2,1,2,1};
        for (int r = 0; r < 5; r++)
            for (int s = r; s < 5; s++) {
                float v = 0.f;
#pragma unroll
                for (int u = 0; u < 6; u++) v += W2U[u] * LDM(r*20+4+u) * LDM(s*20+4+u);
                STrow[f++] = f2b(v);
            }
        // c3: f35..49
        const float W3U[10] = {1,3,3,3,6,3,1,3,3,1};
        for (int r = 0; r < 5; r++)
            for (int s = r; s < 5; s++) {
                float v = 0.f;
#pragma unroll
                for (int u = 0; u < 10; u++) v += W3U[u] * LDM(r*20+10+u) * LDM(s*20+10+u);
                STrow[f++] = f2b(v);
            }
        // c7 groups 13 (r3,s4), 14 (r4,s4)
        do_c7(M, STrow, 3, 4, 160 + 13*5);
        do_c7(M, STrow, 4, 4, 160 + 14*5);
    } else if (wave == 1 || wave == 2) {
        // c4: f50..84, entries 0..17 / 18..34
        const int S2[3][3] = {{0,1,2},{1,3,4},{2,4,5}};
        int e0 = (wave == 1) ? 0 : 18, e1 = (wave == 1) ? 18 : 35;
        int e = 0;
        for (int r = 0; r < 5; r++)
            for (int s = r; s < 5; s++)
                for (int t = s; t < 5; t++) {
                    if (e >= e0 && e < e1) {
                        float m2r[6], m2q[6], m2t[6];
#pragma unroll
                        for (int u = 0; u < 6; u++) m2r[u] = LDM(r*20+4+u);
#pragma unroll
                        for (int u = 0; u < 6; u++) m2q[u] = LDM(s*20+4+u);
#pragma unroll
                        for (int u = 0; u < 6; u++) m2t[u] = LDM(t*20+4+u);
                        float v = 0.f;
#pragma unroll
                        for (int i = 0; i < 3; i++)
#pragma unroll
                            for (int j = 0; j < 3; j++)
#pragma unroll
                                for (int k = 0; k < 3; k++)
                                    v += m2r[S2[i][j]] * m2q[S2[i][k]] * m2t[S2[j][k]];
                        STrow[50 + e] = f2b(v);
                    }
                    e++;
                }
    } else if (wave == 3) {
        // c5 pairs 0..7 (f85..124), c7 group 12 (r3,s3)
        int p = 0;
        for (int r = 0; r < 5; r++)
            for (int s = r; s < 5; s++) {
                if (p < 8) do_c5(M, STrow, r, s, 85 + p*5);
                p++;
            }
        do_c7(M, STrow, 3, 3, 160 + 12*5);
    } else if (wave == 4) {
        // c5 pairs 8..14 (f125..159), c6 group 0 (f235..239)
        int p = 0;
        for (int r = 0; r < 5; r++)
            for (int s = r; s < 5; s++) {
                if (p >= 8) do_c5(M, STrow, r, s, 85 + p*5);
                p++;
            }
        do_c6(M, STrow, 0, 0, 235);
    } else {
        // waves 5/6/7: c7 groups [ (wave-5)*4, +4 )
        int pc0 = (wave - 5) * 4;
        int p = 0;
        for (int r = 0; r < 5; r++)
            for (int s = r; s < 5; s++) {
                if (p >= pc0 && p < pc0 + 4) do_c7(M, STrow, r, s, 160 + p*5);
                p++;
            }
    }
    __syncthreads();
    // flush 0: f0..239 = 120 uints/row, coalesced
    for (int e = tid; e < 64 * 120; e += 512) {
        int row = e / 120, c = e - row * 120;
        if (a0 + row < NA)
            *(unsigned int*)&gmB[(size_t)(a0 + row) * KP1 + 2*c] =
                *(const unsigned int*)&ST[row * 242 + 2*c];
    }
    __syncthreads();

    // ---- phase B pass 1: features 240..383 (c6 groups 1..24 + zero pad) ----
    {
        int g0 = 1 + wave * 3;
        for (int gi = 0; gi < 3; gi++) {
            int gr = g0 + gi;
            int r = gr / 5, s = gr - r * 5;
            do_c6(M, STrow, r, s, 235 + gr*5 - 240);
        }
        if (wave == 0) {
            for (int z = 360; z < 384; z++) STrow[z - 240] = 0;
        }
    }
    __syncthreads();
    // flush 1: f240..383 = 72 uints/row (short-offset 240 within the KP1=384 row)
    for (int e = tid; e < 64 * 72; e += 512) {
        int row = e / 72, c = e - row * 72;
        if (a0 + row < NA)
            *(unsigned int*)&gmB[(size_t)(a0 + row) * KP1 + 240 + 2*c] =
                *(const unsigned int*)&ST[row * 242 + 2*c];
    }
}

// ---------------- MFMA GEMM, XCD-swizzled (R10 best) -----------------------------
// One (atile, colblock) per block; flat grid of 960. Swizzle maps all 4
// colblocks of an atile to the SAME XCD (bid%8) for L2 panel reuse.
// MODE 1: A=atoms(gmB), B=units(w1T); h1B = swish(D + bias[col]).
// MODE 2: A=units(w2T), B=atoms(h1B); fused layer-3 atomicAdd to out.
__device__ __forceinline__ void stage8(const unsigned short* gp, unsigned short* lp) {
    __builtin_amdgcn_global_load_lds(
        (const __attribute__((address_space(1))) unsigned int*)gp,
        (__attribute__((address_space(3))) unsigned int*)lp, 16, 0, 0);
}

template<int KPAD, int MODE>
__global__ __launch_bounds__(256) void k_mfma(const unsigned short* __restrict__ A,
                                              const unsigned short* __restrict__ B,
                                              const float* __restrict__ bias,
                                              const float* __restrict__ w3,
                                              void* __restrict__ outp) {
    // SMEM union: [As 16KB | Bs 16KB | red 1KB]  or  [Ot 128x136 shorts = 34816B]
    __shared__ __align__(16) unsigned char SMEM[35072];
    unsigned short* As = (unsigned short*)SMEM;
    unsigned short* Bs = (unsigned short*)(SMEM + 16384);
    float* red = (float*)(SMEM + 32768);       // [2][2][4][16]
    int tid = threadIdx.x;
    int lane = tid & 63, wave = tid >> 6;
    int wm = wave >> 1, wn = wave & 1;
    int quad = lane >> 4, l16 = lane & 15;
    int lrow = lane >> 3;          // 0..7
    int lchk = lane & 7;           // 16B chunk slot

    // XCD swizzle: bid in [0,960). xcd = bid&7; r = bid>>3 (0..119);
    // colblock = r&3; agrp = r>>2 (0..29); atile = xcd*30 + agrp (0..239).
    int bid = blockIdx.x;
    int xcd = bid & 7, rr_ = bid >> 3;
    int cblk = rr_ & 3, agrp = rr_ >> 2;
    int atile = xcd * 30 + agrp;
    if (atile >= NTILE) return;

    int rowA0, rowB0;
    if (MODE == 1) { rowA0 = atile * 128; rowB0 = cblk * 128; }
    else           { rowA0 = cblk * 128;  rowB0 = atile * 128; }

    f32x4 acc[4][4];
    f32x4 zero = {0.f, 0.f, 0.f, 0.f};
#pragma unroll
    for (int i = 0; i < 4; i++)
#pragma unroll
        for (int j = 0; j < 4; j++) acc[i][j] = zero;

    for (int k0 = 0; k0 < KPAD; k0 += 64) {
        __syncthreads();
#pragma unroll
        for (int i = 0; i < 4; i++) {
            int r = wave * 32 + i * 8 + lrow;
            int gc = lchk ^ (r & 7);
            stage8(A + (size_t)(rowA0 + r) * KPAD + k0 + gc * 8, &As[(wave * 32 + i * 8) * 64]);
        }
#pragma unroll
        for (int i = 0; i < 4; i++) {
            int r = wave * 32 + i * 8 + lrow;
            int gc = lchk ^ (r & 7);
            stage8(B + (size_t)(rowB0 + r) * KPAD + k0 + gc * 8, &Bs[(wave * 32 + i * 8) * 64]);
        }
        __syncthreads();
#pragma unroll
        for (int s = 0; s < 2; s++) {
            bf16x8 af[4], bfr[4];
#pragma unroll
            for (int mt = 0; mt < 4; mt++) {
                int r = wm * 64 + mt * 16 + l16;
                af[mt] = *(const bf16x8*)&As[r * 64 + (((s * 4 + quad) ^ (r & 7)) * 8)];
            }
#pragma unroll
            for (int nt = 0; nt < 4; nt++) {
                int r = wn * 64 + nt * 16 + l16;
                bfr[nt] = *(const bf16x8*)&Bs[r * 64 + (((s * 4 + quad) ^ (r & 7)) * 8)];
            }
#pragma unroll
            for (int mt = 0; mt < 4; mt++)
#pragma unroll
                for (int nt = 0; nt < 4; nt++)
                    acc[mt][nt] = __builtin_amdgcn_mfma_f32_16x16x32_bf16(
                        af[mt], bfr[nt], acc[mt][nt], 0, 0, 0);
        }
    }

    if (MODE == 1) {
        // stage swish output tile in LDS (stride 136 shorts), then coalesced store
        __syncthreads();   // all waves done reading As/Bs
        unsigned short* Ot = (unsigned short*)SMEM;
#pragma unroll
        for (int nt = 0; nt < 4; nt++) {
            int c_loc = wn * 64 + nt * 16 + l16;
            float b = bias[rowB0 + c_loc];
#pragma unroll
            for (int mt = 0; mt < 4; mt++) {
#pragma unroll
                for (int reg = 0; reg < 4; reg++) {
                    int a_loc = wm * 64 + mt * 16 + quad * 4 + reg;
                    float v = acc[mt][nt][reg] + b;
                    Ot[a_loc * 136 + c_loc] = f2b(v / (1.f + __expf(-v)));
                }
            }
        }
        __syncthreads();
        unsigned short* O = (unsigned short*)outp;
        int half = lane >> 5, l32 = lane & 31;
#pragma unroll
        for (int it = 0; it < 16; it++) {
            int rloc = wave * 32 + it * 2 + half;
            int a = rowA0 + rloc;
            unsigned long long d = *(const unsigned long long*)&Ot[rloc * 136 + l32 * 4];
            if (a < NA)
                *(unsigned long long*)&O[(size_t)a * NU + rowB0 + l32 * 4] = d;
        }
    } else {
        // fused layer-3 partial dot: per-lane over its 16 c's, quad + wm reduce
        float pn[4] = {0.f, 0.f, 0.f, 0.f};
#pragma unroll
        for (int mt = 0; mt < 4; mt++) {
#pragma unroll
            for (int reg = 0; reg < 4; reg++) {
                int c = rowA0 + wm * 64 + mt * 16 + quad * 4 + reg;
                float b = bias[c];
                float w3c = w3[c];
#pragma unroll
                for (int nt = 0; nt < 4; nt++) {
                    float v = acc[mt][nt][reg] + b;
                    pn[nt] += w3c * (v / (1.f + __expf(-v)));
                }
            }
        }
#pragma unroll
        for (int nt = 0; nt < 4; nt++) {
            pn[nt] += __shfl_xor(pn[nt], 16);
            pn[nt] += __shfl_xor(pn[nt], 32);
        }
        __syncthreads();   // As/Bs done; red region safe
        if (quad == 0) {
#pragma unroll
            for (int nt = 0; nt < 4; nt++)
                red[((wm * 2 + wn) * 4 + nt) * 16 + l16] = pn[nt];
        }
        __syncthreads();
        if (tid < 128) {
            int wn2 = tid >> 6, nt2 = (tid >> 4) & 3, lb = tid & 15;
            float s = red[((0 * 2 + wn2) * 4 + nt2) * 16 + lb]
                    + red[((1 * 2 + wn2) * 4 + nt2) * 16 + lb];
            int a = rowB0 + wn2 * 64 + nt2 * 16 + lb;
            if (a < NA) atomicAdd((float*)outp + a, s);
        }
    }
}

// ---------------- finish: out = scale[Z]*(out + b3) + shift[Z] ----------------
__global__ void k_finish(float* __restrict__ out, const float* __restrict__ b3,
                         const int* __restrict__ Z, const float* __restrict__ scale,
                         const float* __restrict__ shift) {
    int a = blockIdx.x * blockDim.x + threadIdx.x;
    if (a >= NA) return;
    int z = Z[a];
    out[a] = scale[z] * (out[a] + b3[0]) + shift[z];
}

extern "C" void kernel_launch(void* const* d_in, const int* in_sizes, int n_in,
                              void* d_out, int out_size, void* d_ws, size_t ws_size,
                              hipStream_t stream) {
    const float* R    = (const float*)d_in[0];
    const int*   Z    = (const int*)  d_in[1];
    const int*   idx  = (const int*)  d_in[2];
    const float* Wr   = (const float*)d_in[3];
    const float* w1   = (const float*)d_in[4];
    const float* b1   = (const float*)d_in[5];
    const float* w2   = (const float*)d_in[6];
    const float* b2   = (const float*)d_in[7];
    const float* w3   = (const float*)d_in[8];
    const float* b3   = (const float*)d_in[9];
    const float* scale= (const float*)d_in[10];
    const float* shift= (const float*)d_in[11];
    float* out = (float*)d_out;
    char* ws = (char*)d_ws;

    // workspace layout (bytes)
    int*            gcur   = (int*)  (ws + 0);           // 1024
    int*            part   = (int*)  (ws + 121024);      // 5414400 (fine buckets)
    unsigned short* gmB    = (unsigned short*)(ws + 32918016);  // 23101440 -> 56019456
    unsigned short* w1T    = (unsigned short*)(ws + 56019456);  // 393216 -> 56412672
    unsigned short* w2T    = (unsigned short*)(ws + 56412672);  // 524288 -> 56936960
    unsigned short* h1B    = (unsigned short*)(ws + 56936960);  // 30801920 -> 87738880
    unsigned short* WpH    = (unsigned short*)(ws + 87738880);  // 1132880 (fp16 W k-major)
    float*          Rpad   = (float*)(ws + 89778064);    // 480000 -> 90258064

    // 6 graph nodes: prep(+zeros), part, momcon(+csr), gemm1, gemm2, finish
    k_prep   <<<(PREP_TOT + 255) / 256, 256, 0, stream>>>(Wr, R, w1, w2, WpH, Rpad,
                                                          w1T, w2T, gcur, out);
    k_part   <<<256, 256, 0, stream>>>(idx, Z, gcur, part);
    k_momcon <<<(NA + 63) / 64, 512, 0, stream>>>(Rpad, Z, WpH, gcur, part, gmB);

    k_mfma<KP1, 1><<<960, 256, 0, stream>>>(gmB, w1T, b1, nullptr, (void*)h1B);
    k_mfma<NU,  2><<<960, 256, 0, stream>>>(w2T, h1B, b2, w3, (void*)out);

    k_finish<<<(NA + 255) / 256, 256, 0, stream>>>(out, b3, Z, scale, shift);
}

// Round 18
// 228.847 us; speedup vs baseline: 1.0080x; 1.0080x over previous
//
#include <hip/hip_runtime.h>

#define NA      30000
#define MPAD    30080            // 235 * 128
#define NPAIRS  1200000
#define NB      7
#define NK      5
#define NSP     119
#define NFEAT   360
#define KP1     384              // NFEAT padded to 64
#define NU      512
#define WROWH   40               // padded W row: 5 k-groups x 8 halfs (80B, 16B aligned)
#define MAXSLOT 120              // slots per atom (Poisson(40): P(deg>120) ~ 0)
#define LPSTR   136              // lp row stride in ints (≡8 mod 32 -> 2-way, free)
#define NBKF    469              // fine buckets of 64 atoms (R18: 1:1 with momcon blocks)
#define BCAPF   3072             // entries per bucket (mean 2559, sd ~51; +10 sigma)
#define PPB     4688             // pairs per partition block (256 blocks)
#define NTILE   235              // 128-atom tiles

#define BETTA      1.3611111111111112f     // 49/36
#define RADNORM    0.96481348f             // (2*betta/pi)^0.25
#define SHIFT_STEP 0.7857142857142857f     // 5.5/7
#define PI_OVER_R  0.5235987755982988f     // pi/6
#define INV_SQRT7  0.3779644730092272f
#define RMAXV      6.0f
#define TCOEF      2.138888888888889f      // 2*betta*h, h = 5.5/7

typedef __attribute__((ext_vector_type(8))) short bf16x8;
typedef __attribute__((ext_vector_type(4))) float f32x4;
typedef __attribute__((ext_vector_type(2))) float f32x2;
typedef __attribute__((ext_vector_type(4))) unsigned int u32x4;
typedef _Float16 h16x2 __attribute__((ext_vector_type(2)));

__device__ __forceinline__ unsigned short f2b(float x) {
    unsigned u = __float_as_uint(x);
    unsigned r = u + 0x7FFF + ((u >> 16) & 1);   // RNE (inputs are finite)
    return (unsigned short)(r >> 16);
}

// ---------------- phase 1: partition pairs into 469 fine buckets (R18) -----------
// entry pack: (i&63)<<22 | Zj<<15 | j   (iloc 6b, Zj 7b, j 15b); bucket = i>>6
__global__ __launch_bounds__(256)
void k_part(const int* __restrict__ idx, const int* __restrict__ Z,
            int* __restrict__ gcur, int* __restrict__ part) {
    __shared__ int hist[NBKF];
    __shared__ int base[NBKF];
    int tid = threadIdx.x;
    for (int b = tid; b < NBKF; b += 256) hist[b] = 0;
    __syncthreads();
    int p0 = blockIdx.x * PPB;
    int p1 = min(p0 + PPB, NPAIRS);
    for (int p = p0 + tid; p < p1; p += 256)
        atomicAdd(&hist[idx[p] >> 6], 1);
    __syncthreads();
    for (int b = tid; b < NBKF; b += 256) {
        base[b] = atomicAdd(&gcur[b], hist[b]);
        hist[b] = 0;
    }
    __syncthreads();
    for (int p = p0 + tid; p < p1; p += 256) {
        int i = idx[p];
        int b = i >> 6;
        int j = idx[NPAIRS + p];
        int zj = Z[j];
        int off = base[b] + atomicAdd(&hist[b], 1);
        if (off < BCAPF)
            part[b * BCAPF + off] = ((i & 63) << 22) | (zj << 15) | j;
    }
}

// ------- merged prep (runs FIRST): zero gcur + d_out, pad W(fp16 k-major)/R ------
#define PREP_W   (NSP*NSP*WROWH)         // 566440 (fp16 elements)
#define PREP_R   NA                      // 30000
#define PREP_W1  (NU*KP1)                // 196608
#define PREP_W2  (NU*NU)                 // 262144
#define PREP_TOT (PREP_W + PREP_R + PREP_W1 + PREP_W2)
__global__ void k_prep(const float* __restrict__ W, const float* __restrict__ R,
                       const float* __restrict__ w1, const float* __restrict__ w2,
                       unsigned short* __restrict__ Wp, float* __restrict__ Rp,
                       unsigned short* __restrict__ w1T, unsigned short* __restrict__ w2T,
                       int* __restrict__ gcur, float* __restrict__ out) {
    int i = blockIdx.x * blockDim.x + threadIdx.x;
    if (i < 512) gcur[i] = 0;            // 469 fine-bucket cursors (padded)
    if (i < NA) out[i] = 0.f;            // layer-3 accumulator
    if (i < PREP_W) {
        // k-major layout: element e = k*8 + b (b<7 real, b=7 zero pad) -> fdot2 pairs
        int row = i / WROWH, e = i - row * WROWH;
        int k = e >> 3, b = e & 7;
        float v = (b < 7) ? W[row * (NK * NB) + k * NB + b] : 0.f;
        ((_Float16*)Wp)[i] = (_Float16)v;   // RNE f32->f16
        return;
    }
    i -= PREP_W;
    if (i < PREP_R) {
        f32x4 v = {R[3*i], R[3*i+1], R[3*i+2], 0.f};
        *(f32x4*)&Rp[4*i] = v;
        return;
    }
    i -= PREP_R;
    if (i < PREP_W1) {
        int c = i / KP1, kp = i - c * KP1;
        w1T[i] = (kp < NFEAT) ? f2b(w1[kp * NU + c]) : (unsigned short)0;
        return;
    }
    i -= PREP_W1;
    if (i < PREP_W2) {
        int c = i >> 9, kp = i & 511;
        w2T[i] = f2b(w2[kp * NU + c]);
    }
}

// ---------------- phase-B contraction helpers (MS is read via M = MS + lane) -----
#define LDM(comp) M[(comp) * 65]

__device__ __forceinline__ void do_c5(const float* M, unsigned short* STrow,
                                      int r, int s, int foff) {
    const int S2[3][3] = {{0,1,2},{1,3,4},{2,4,5}};
    float m1r[3], m1q[3];
#pragma unroll
    for (int i = 0; i < 3; i++) m1r[i] = LDM(r*20+1+i);
#pragma unroll
    for (int i = 0; i < 3; i++) m1q[i] = LDM(s*20+1+i);
    float pre[9];
#pragma unroll
    for (int i = 0; i < 3; i++)
#pragma unroll
        for (int j = 0; j < 3; j++) pre[i*3+j] = m1r[i] * m1q[j];
    for (int t = 0; t < 5; t++) {
        float m2t[6];
#pragma unroll
        for (int u = 0; u < 6; u++) m2t[u] = LDM(t*20+4+u);
        float v = 0.f;
#pragma unroll
        for (int i = 0; i < 3; i++)
#pragma unroll
            for (int j = 0; j < 3; j++)
                v += pre[i*3+j] * m2t[S2[i][j]];
        STrow[foff + t] = f2b(v);
    }
}

__device__ __forceinline__ void do_c6(const float* M, unsigned short* STrow,
                                      int r, int s, int foff) {
    const int S2[3][3] = {{0,1,2},{1,3,4},{2,4,5}};
    const int S3[3][3][3] = {
        {{0,1,2},{1,3,4},{2,4,5}},
        {{1,3,4},{3,6,7},{4,7,8}},
        {{2,4,5},{4,7,8},{5,8,9}}
    };
    float m3r[10];
#pragma unroll
    for (int u = 0; u < 10; u++) m3r[u] = LDM(r*20+10+u);
    float m2q[6];
#pragma unroll
    for (int u = 0; u < 6; u++) m2q[u] = LDM(s*20+4+u);
    float U0 = 0.f, U1 = 0.f, U2 = 0.f;
#pragma unroll
    for (int i = 0; i < 3; i++)
#pragma unroll
        for (int j = 0; j < 3; j++) {
            float ww = m2q[S2[i][j]];
            U0 += m3r[S3[i][j][0]] * ww;
            U1 += m3r[S3[i][j][1]] * ww;
            U2 += m3r[S3[i][j][2]] * ww;
        }
    for (int t = 0; t < 5; t++) {
        float v = U0 * LDM(t*20+1) + U1 * LDM(t*20+2) + U2 * LDM(t*20+3);
        STrow[foff + t] = f2b(v);
    }
}

__device__ __forceinline__ void do_c7(const float* M, unsigned short* STrow,
                                      int r, int s, int foff) {
    const int S2[3][3] = {{0,1,2},{1,3,4},{2,4,5}};
    const int S3[3][3][3] = {
        {{0,1,2},{1,3,4},{2,4,5}},
        {{1,3,4},{3,6,7},{4,7,8}},
        {{2,4,5},{4,7,8},{5,8,9}}
    };
    float m3r[10], m3q[10];
#pragma unroll
    for (int u = 0; u < 10; u++) m3r[u] = LDM(r*20+10+u);
#pragma unroll
    for (int u = 0; u < 10; u++) m3q[u] = LDM(s*20+10+u);
    float T[3][3];
#pragma unroll
    for (int k = 0; k < 3; k++)
#pragma unroll
        for (int l = 0; l < 3; l++) {
            float v = 0.f;
#pragma unroll
            for (int i = 0; i < 3; i++)
#pragma unroll
                for (int j = 0; j < 3; j++)
                    v += m3r[S3[i][j][k]] * m3q[S3[i][j][l]];
            T[k][l] = v;
        }
    for (int t = 0; t < 5; t++) {
        float m2t[6];
#pragma unroll
        for (int u = 0; u < 6; u++) m2t[u] = LDM(t*20+4+u);
        float v = 0.f;
#pragma unroll
        for (int k = 0; k < 3; k++)
#pragma unroll
            for (int l = 0; l < 3; l++)
                v += T[k][l] * m2t[S2[k][l]];
        STrow[foff + t] = f2b(v);
    }
}

// ------- fused CSR + moments + contraction (R15-R18) -----------------------------
// A0: block = 64 atoms = ONE fine bucket (R18: 1:1, no half filter, every
//   entry read belongs to this block — scan reads and iterations halved vs
//   128-atom buckets). lp[64][LPSTR], stride 136 (≡8 mod 32: 2-way banks, free).
// Phase A: R5/R8 pair loop, prow read from LDS (lp row).
// Phase B: unchanged (balanced feature split -> ST -> coalesced flushes).
// LDS: MS [0,26000) | lp [26000,60816) (A) / ST [26000,56976) (B) | lc [60816,61072).
//   61072B -> 2 blocks/CU.
__global__ __launch_bounds__(512, 2)
void k_momcon(const float* __restrict__ Rp, const int* __restrict__ Z,
              const unsigned short* __restrict__ WpH, const int* __restrict__ gcnt,
              const int* __restrict__ part, unsigned short* __restrict__ gmB) {
    __shared__ __align__(16) unsigned char LDSM[61072];
    float* MS = (float*)LDSM;                              // [100*65] f32
    int* lp = (int*)(LDSM + 26000);                        // [64][LPSTR] ints (phase A)
    unsigned short* ST = (unsigned short*)(LDSM + 26000);  // [64][242] (phase B)
    int* lc = (int*)(LDSM + 60816);                        // [64]
    int tid = threadIdx.x;
    int a0 = blockIdx.x * 64;

    // ---- A0: build CSR rows for this block's 64 atoms from its own bucket ----
    {
        int bkt = blockIdx.x;           // fine bucket == block (64 atoms)
        for (int t = tid; t < 64; t += 512) lc[t] = 0;
        __syncthreads();
        int n = min(gcnt[bkt], BCAPF);
        for (int e = tid; e < n; e += 512) {
            int v = part[bkt * BCAPF + e];
            int i6 = v >> 22;           // 0..63
            int r = atomicAdd(&lc[i6], 1);
            if (r < MAXSLOT) lp[i6 * LPSTR + r] = v & 0x3FFFFF;  // Zj<<15 | j
        }
        __syncthreads();
    }

    int g = tid >> 3, q = tid & 7;      // local atom 0..63, lane-in-group
    int a = a0 + g;

    if (a < NA) {
        f32x4 ri = *(const f32x4*)&Rp[4*a];
        int Zi = Z[a];
        f32x2 acc[50];
#pragma unroll
        for (int u = 0; u < 50; u++) acc[u] = (f32x2){0.f, 0.f};
        int cnt = min(lc[g], MAXSLOT);
        const int* prow = lp + g * LPSTR;

        // basis recurrence constants: D[b] = exp(-betah*(1 + h*(2b+1)))
        const float DCH[6] = {0.14812156f, 0.027590652f, 0.0051393300f,
                              0.00095730500f, 0.00017831700f, 3.3215300e-05f};

        // software pipeline: pk two ahead, rj one ahead (clamped garbage-safe)
        int pk0 = prow[q & 127];
        int pk1 = prow[(q + 8) & 127];
        int j0c = min(pk0 & 0x7FFF, NA - 1);
        f32x4 rj = *(const f32x4*)&Rp[4 * j0c];

        for (int t = q; t < cnt; t += 8) {
            int pk2 = prow[(t + 16) & 127];
            int j1c = min(pk1 & 0x7FFF, NA - 1);
            f32x4 rjn = *(const f32x4*)&Rp[4 * j1c];     // prefetch next pair

            int Zj = (pk0 >> 15) & 0x7F;                 // pk0 valid (t < cnt)
            const u32x4* wv = (const u32x4*)(WpH + (size_t)(Zi * NSP + Zj) * WROWH);
            u32x4 wv0 = wv[0], wv1 = wv[1], wv2 = wv[2], wv3 = wv[3], wv4 = wv[4];
            unsigned wu[20];
#pragma unroll
            for (int c = 0; c < 4; c++) {
                wu[c]      = wv0[c];
                wu[4 + c]  = wv1[c];
                wu[8 + c]  = wv2[c];
                wu[12 + c] = wv3[c];
                wu[16 + c] = wv4[c];
            }

            float dx = rj.x - ri.x, dy = rj.y - ri.y, dz = rj.z - ri.z;
            float d2 = dx*dx + dy*dy + dz*dz + 1e-12f;
            float dr = sqrtf(d2);
            float inv = 1.0f / (dr + 1e-5f);
            float nx = dx*inv, ny = dy*inv, nz = dz*inv;

            // basis via recurrence: bb[b+1] = bb[b] * T * D[b]
            float t0 = dr - 0.5f;
            float bb[NB];
            bb[0] = RADNORM * __expf(-BETTA * t0 * t0);
            float Tg = __expf(TCOEF * dr);
#pragma unroll
            for (int b = 0; b < 6; b++) bb[b+1] = bb[b] * Tg * DCH[b];

            float cut = (dr < RMAXV) ? 0.5f * (__cosf(PI_OVER_R * dr) + 1.0f) : 0.0f;
            cut *= INV_SQRT7;

            h16x2 bp[4];
            bp[0] = (h16x2){(_Float16)bb[0], (_Float16)bb[1]};
            bp[1] = (h16x2){(_Float16)bb[2], (_Float16)bb[3]};
            bp[2] = (h16x2){(_Float16)bb[4], (_Float16)bb[5]};
            bp[3] = (h16x2){(_Float16)bb[6], (_Float16)0.0f};

            float rad[NK];
#pragma unroll
            for (int k = 0; k < NK; k++) {
                float s = 0.f;
#if __has_builtin(__builtin_amdgcn_fdot2)
#pragma unroll
                for (int c = 0; c < 4; c++)
                    s = __builtin_amdgcn_fdot2(
                        __builtin_bit_cast(h16x2, wu[k*4 + c]), bp[c], s, false);
#else
#pragma unroll
                for (int c = 0; c < 4; c++) {
                    h16x2 w = __builtin_bit_cast(h16x2, wu[k*4 + c]);
                    s += (float)w.x * (float)bp[c].x + (float)w.y * (float)bp[c].y;
                }
#endif
                rad[k] = s * cut;
            }

            float gg[20];
            gg[0] = 1.f; gg[1] = nx; gg[2] = ny; gg[3] = nz;
            gg[4] = nx*nx; gg[5] = nx*ny; gg[6] = nx*nz; gg[7] = ny*ny; gg[8] = ny*nz; gg[9] = nz*nz;
            gg[10] = gg[4]*nx; gg[11] = gg[4]*ny; gg[12] = gg[4]*nz; gg[13] = gg[5]*ny; gg[14] = gg[5]*nz;
            gg[15] = gg[6]*nz; gg[16] = gg[7]*ny; gg[17] = gg[7]*nz; gg[18] = gg[8]*nz; gg[19] = gg[9]*nz;
            f32x2 g2[10];
#pragma unroll
            for (int u = 0; u < 10; u++) g2[u] = (f32x2){gg[2*u], gg[2*u+1]};
#pragma unroll
            for (int k = 0; k < NK; k++) {
                f32x2 rk = (f32x2){rad[k], rad[k]};
#pragma unroll
                for (int u = 0; u < 10; u++)
                    acc[k*10 + u] += rk * g2[u];      // v_pk_fma_f32
            }
            pk0 = pk1; pk1 = pk2; rj = rjn;
        }
        // reduce within the 8-lane group as 64-bit packets
#pragma unroll
        for (int u = 0; u < 50; u++) {
            f32x2 v = acc[u];
            double d = __builtin_bit_cast(double, v);
            d = __shfl_xor(d, 1);
            v += __builtin_bit_cast(f32x2, d);
            d = __builtin_bit_cast(double, v);
            d = __shfl_xor(d, 2);
            v += __builtin_bit_cast(f32x2, d);
            d = __builtin_bit_cast(double, v);
            d = __shfl_xor(d, 4);
            v += __builtin_bit_cast(f32x2, d);
            acc[u] = v;
        }
        if (q == 0) {
#pragma unroll
            for (int u = 0; u < 50; u++) {
                MS[(2*u)     * 65 + g] = acc[u].x;
                MS[(2*u + 1) * 65 + g] = acc[u].y;
            }
        }
    }
    __syncthreads();                    // phase A done; lp dead, MS ready

    // ---- phase B pass 0: features 0..239 into ST, balanced over 8 waves ----
    int lane = tid & 63, wave = tid >> 6;
    const float* M = MS + lane;
    unsigned short* STrow = ST + lane * 242;

    if (wave == 0) {
        // m0: f0..4
        for (int k = 0; k < 5; k++) STrow[k] = f2b(LDM(k * 20));
        // c1: f5..19
        int f = 5;
        for (int r = 0; r < 5; r++)
            for (int s = r; s < 5; s++) {
                float v = 0.f;
#pragma unroll
                for (int i = 0; i < 3; i++) v += LDM(r*20+1+i) * LDM(s*20+1+i);
                STrow[f++] = f2b(v);
            }
        // c2: f20..34
        const float W2U[6] = {1,2,2,1,2,1};
        for (int r = 0; r < 5; r++)
            for (int s = r; s < 5; s++) {
                float v = 0.f;
#pragma unroll
                for (int u = 0; u < 6; u++) v += W2U[u] * LDM(r*20+4+u) * LDM(s*20+4+u);
                STrow[f++] = f2b(v);
            }
        // c3: f35..49
        const float W3U[10] = {1,3,3,3,6,3,1,3,3,1};
        for (int r = 0; r < 5; r++)
            for (int s = r; s < 5; s++) {
                float v = 0.f;
#pragma unroll
                for (int u = 0; u < 10; u++) v += W3U[u] * LDM(r*20+10+u) * LDM(s*20+10+u);
                STrow[f++] = f2b(v);
            }
        // c7 groups 13 (r3,s4), 14 (r4,s4)
        do_c7(M, STrow, 3, 4, 160 + 13*5);
        do_c7(M, STrow, 4, 4, 160 + 14*5);
    } else if (wave == 1 || wave == 2) {
        // c4: f50..84, entries 0..17 / 18..34
        const int S2[3][3] = {{0,1,2},{1,3,4},{2,4,5}};
        int e0 = (wave == 1) ? 0 : 18, e1 = (wave == 1) ? 18 : 35;
        int e = 0;
        for (int r = 0; r < 5; r++)
            for (int s = r; s < 5; s++)
                for (int t = s; t < 5; t++) {
                    if (e >= e0 && e < e1) {
                        float m2r[6], m2q[6], m2t[6];
#pragma unroll
                        for (int u = 0; u < 6; u++) m2r[u] = LDM(r*20+4+u);
#pragma unroll
                        for (int u = 0; u < 6; u++) m2q[u] = LDM(s*20+4+u);
#pragma unroll
                        for (int u = 0; u < 6; u++) m2t[u] = LDM(t*20+4+u);
                        float v = 0.f;
#pragma unroll
                        for (int i = 0; i < 3; i++)
#pragma unroll
                            for (int j = 0; j < 3; j++)
#pragma unroll
                                for (int k = 0; k < 3; k++)
                                    v += m2r[S2[i][j]] * m2q[S2[i][k]] * m2t[S2[j][k]];
                        STrow[50 + e] = f2b(v);
                    }
                    e++;
                }
    } else if (wave == 3) {
        // c5 pairs 0..7 (f85..124), c7 group 12 (r3,s3)
        int p = 0;
        for (int r = 0; r < 5; r++)
            for (int s = r; s < 5; s++) {
                if (p < 8) do_c5(M, STrow, r, s, 85 + p*5);
                p++;
            }
        do_c7(M, STrow, 3, 3, 160 + 12*5);
    } else if (wave == 4) {
        // c5 pairs 8..14 (f125..159), c6 group 0 (f235..239)
        int p = 0;
        for (int r = 0; r < 5; r++)
            for (int s = r; s < 5; s++) {
                if (p >= 8) do_c5(M, STrow, r, s, 85 + p*5);
                p++;
            }
        do_c6(M, STrow, 0, 0, 235);
    } else {
        // waves 5/6/7: c7 groups [ (wave-5)*4, +4 )
        int pc0 = (wave - 5) * 4;
        int p = 0;
        for (int r = 0; r < 5; r++)
            for (int s = r; s < 5; s++) {
                if (p >= pc0 && p < pc0 + 4) do_c7(M, STrow, r, s, 160 + p*5);
                p++;
            }
    }
    __syncthreads();
    // flush 0: f0..239 = 120 uints/row, coalesced
    for (int e = tid; e < 64 * 120; e += 512) {
        int row = e / 120, c = e - row * 120;
        if (a0 + row < NA)
            *(unsigned int*)&gmB[(size_t)(a0 + row) * KP1 + 2*c] =
                *(const unsigned int*)&ST[row * 242 + 2*c];
    }
    __syncthreads();

    // ---- phase B pass 1: features 240..383 (c6 groups 1..24 + zero pad) ----
    {
        int g0 = 1 + wave * 3;
        for (int gi = 0; gi < 3; gi++) {
            int gr = g0 + gi;
            int r = gr / 5, s = gr - r * 5;
            do_c6(M, STrow, r, s, 235 + gr*5 - 240);
        }
        if (wave == 0) {
            for (int z = 360; z < 384; z++) STrow[z - 240] = 0;
        }
    }
    __syncthreads();
    // flush 1: f240..383 = 72 uints/row (short-offset 240 within the KP1=384 row)
    for (int e = tid; e < 64 * 72; e += 512) {
        int row = e / 72, c = e - row * 72;
        if (a0 + row < NA)
            *(unsigned int*)&gmB[(size_t)(a0 + row) * KP1 + 240 + 2*c] =
                *(const unsigned int*)&ST[row * 242 + 2*c];
    }
}

// ---------------- MFMA GEMM, XCD-swizzled (R10 best) -----------------------------
// One (atile, colblock) per block; flat grid of 960. Swizzle maps all 4
// colblocks of an atile to the SAME XCD (bid%8) for L2 panel reuse.
// MODE 1: A=atoms(gmB), B=units(w1T); h1B = swish(D + bias[col]).
// MODE 2: A=units(w2T), B=atoms(h1B); fused layer-3 atomicAdd to out.
__device__ __forceinline__ void stage8(const unsigned short* gp, unsigned short* lp) {
    __builtin_amdgcn_global_load_lds(
        (const __attribute__((address_space(1))) unsigned int*)gp,
        (__attribute__((address_space(3))) unsigned int*)lp, 16, 0, 0);
}

template<int KPAD, int MODE>
__global__ __launch_bounds__(256) void k_mfma(const unsigned short* __restrict__ A,
                                              const unsigned short* __restrict__ B,
                                              const float* __restrict__ bias,
                                              const float* __restrict__ w3,
                                              void* __restrict__ outp) {
    // SMEM union: [As 16KB | Bs 16KB | red 1KB]  or  [Ot 128x136 shorts = 34816B]
    __shared__ __align__(16) unsigned char SMEM[35072];
    unsigned short* As = (unsigned short*)SMEM;
    unsigned short* Bs = (unsigned short*)(SMEM + 16384);
    float* red = (float*)(SMEM + 32768);       // [2][2][4][16]
    int tid = threadIdx.x;
    int lane = tid & 63, wave = tid >> 6;
    int wm = wave >> 1, wn = wave & 1;
    int quad = lane >> 4, l16 = lane & 15;
    int lrow = lane >> 3;          // 0..7
    int lchk = lane & 7;           // 16B chunk slot

    // XCD swizzle: bid in [0,960). xcd = bid&7; r = bid>>3 (0..119);
    // colblock = r&3; agrp = r>>2 (0..29); atile = xcd*30 + agrp (0..239).
    int bid = blockIdx.x;
    int xcd = bid & 7, rr_ = bid >> 3;
    int cblk = rr_ & 3, agrp = rr_ >> 2;
    int atile = xcd * 30 + agrp;
    if (atile >= NTILE) return;

    int rowA0, rowB0;
    if (MODE == 1) { rowA0 = atile * 128; rowB0 = cblk * 128; }
    else           { rowA0 = cblk * 128;  rowB0 = atile * 128; }

    f32x4 acc[4][4];
    f32x4 zero = {0.f, 0.f, 0.f, 0.f};
#pragma unroll
    for (int i = 0; i < 4; i++)
#pragma unroll
        for (int j = 0; j < 4; j++) acc[i][j] = zero;

    for (int k0 = 0; k0 < KPAD; k0 += 64) {
        __syncthreads();
#pragma unroll
        for (int i = 0; i < 4; i++) {
            int r = wave * 32 + i * 8 + lrow;
            int gc = lchk ^ (r & 7);
            stage8(A + (size_t)(rowA0 + r) * KPAD + k0 + gc * 8, &As[(wave * 32 + i * 8) * 64]);
        }
#pragma unroll
        for (int i = 0; i < 4; i++) {
            int r = wave * 32 + i * 8 + lrow;
            int gc = lchk ^ (r & 7);
            stage8(B + (size_t)(rowB0 + r) * KPAD + k0 + gc * 8, &Bs[(wave * 32 + i * 8) * 64]);
        }
        __syncthreads();
#pragma unroll
        for (int s = 0; s < 2; s++) {
            bf16x8 af[4], bfr[4];
#pragma unroll
            for (int mt = 0; mt < 4; mt++) {
                int r = wm * 64 + mt * 16 + l16;
                af[mt] = *(const bf16x8*)&As[r * 64 + (((s * 4 + quad) ^ (r & 7)) * 8)];
            }
#pragma unroll
            for (int nt = 0; nt < 4; nt++) {
                int r = wn * 64 + nt * 16 + l16;
                bfr[nt] = *(const bf16x8*)&Bs[r * 64 + (((s * 4 + quad) ^ (r & 7)) * 8)];
            }
#pragma unroll
            for (int mt = 0; mt < 4; mt++)
#pragma unroll
                for (int nt = 0; nt < 4; nt++)
                    acc[mt][nt] = __builtin_amdgcn_mfma_f32_16x16x32_bf16(
                        af[mt], bfr[nt], acc[mt][nt], 0, 0, 0);
        }
    }

    if (MODE == 1) {
        // stage swish output tile in LDS (stride 136 shorts), then coalesced store
        __syncthreads();   // all waves done reading As/Bs
        unsigned short* Ot = (unsigned short*)SMEM;
#pragma unroll
        for (int nt = 0; nt < 4; nt++) {
            int c_loc = wn * 64 + nt * 16 + l16;
            float b = bias[rowB0 + c_loc];
#pragma unroll
            for (int mt = 0; mt < 4; mt++) {
#pragma unroll
                for (int reg = 0; reg < 4; reg++) {
                    int a_loc = wm * 64 + mt * 16 + quad * 4 + reg;
                    float v = acc[mt][nt][reg] + b;
                    Ot[a_loc * 136 + c_loc] = f2b(v / (1.f + __expf(-v)));
                }
            }
        }
        __syncthreads();
        unsigned short* O = (unsigned short*)outp;
        int half = lane >> 5, l32 = lane & 31;
#pragma unroll
        for (int it = 0; it < 16; it++) {
            int rloc = wave * 32 + it * 2 + half;
            int a = rowA0 + rloc;
            unsigned long long d = *(const unsigned long long*)&Ot[rloc * 136 + l32 * 4];
            if (a < NA)
                *(unsigned long long*)&O[(size_t)a * NU + rowB0 + l32 * 4] = d;
        }
    } else {
        // fused layer-3 partial dot: per-lane over its 16 c's, quad + wm reduce
        float pn[4] = {0.f, 0.f, 0.f, 0.f};
#pragma unroll
        for (int mt = 0; mt < 4; mt++) {
#pragma unroll
            for (int reg = 0; reg < 4; reg++) {
                int c = rowA0 + wm * 64 + mt * 16 + quad * 4 + reg;
                float b = bias[c];
                float w3c = w3[c];
#pragma unroll
                for (int nt = 0; nt < 4; nt++) {
                    float v = acc[mt][nt][reg] + b;
                    pn[nt] += w3c * (v / (1.f + __expf(-v)));
                }
            }
        }
#pragma unroll
        for (int nt = 0; nt < 4; nt++) {
            pn[nt] += __shfl_xor(pn[nt], 16);
            pn[nt] += __shfl_xor(pn[nt], 32);
        }
        __syncthreads();   // As/Bs done; red region safe
        if (quad == 0) {
#pragma unroll
            for (int nt = 0; nt < 4; nt++)
                red[((wm * 2 + wn) * 4 + nt) * 16 + l16] = pn[nt];
        }
        __syncthreads();
        if (tid < 128) {
            int wn2 = tid >> 6, nt2 = (tid >> 4) & 3, lb = tid & 15;
            float s = red[((0 * 2 + wn2) * 4 + nt2) * 16 + lb]
                    + red[((1 * 2 + wn2) * 4 + nt2) * 16 + lb];
            int a = rowB0 + wn2 * 64 + nt2 * 16 + lb;
            if (a < NA) atomicAdd((float*)outp + a, s);
        }
    }
}

// ---------------- finish: out = scale[Z]*(out + b3) + shift[Z] ----------------
__global__ void k_finish(float* __restrict__ out, const float* __restrict__ b3,
                         const int* __restrict__ Z, const float* __restrict__ scale,
                         const float* __restrict__ shift) {
    int a = blockIdx.x * blockDim.x + threadIdx.x;
    if (a >= NA) return;
    int z = Z[a];
    out[a] = scale[z] * (out[a] + b3[0]) + shift[z];
}

extern "C" void kernel_launch(void* const* d_in, const int* in_sizes, int n_in,
                              void* d_out, int out_size, void* d_ws, size_t ws_size,
                              hipStream_t stream) {
    const float* R    = (const float*)d_in[0];
    const int*   Z    = (const int*)  d_in[1];
    const int*   idx  = (const int*)  d_in[2];
    const float* Wr   = (const float*)d_in[3];
    const float* w1   = (const float*)d_in[4];
    const float* b1   = (const float*)d_in[5];
    const float* w2   = (const float*)d_in[6];
    const float* b2   = (const float*)d_in[7];
    const float* w3   = (const float*)d_in[8];
    const float* b3   = (const float*)d_in[9];
    const float* scale= (const float*)d_in[10];
    const float* shift= (const float*)d_in[11];
    float* out = (float*)d_out;
    char* ws = (char*)d_ws;

    // workspace layout (bytes)
    int*            gcur   = (int*)  (ws + 0);           // 2048
    int*            part   = (int*)  (ws + 121024);      // 469*3072*4 = 5763072
    unsigned short* gmB    = (unsigned short*)(ws + 32918016);  // 23101440 -> 56019456
    unsigned short* w1T    = (unsigned short*)(ws + 56019456);  // 393216 -> 56412672
    unsigned short* w2T    = (unsigned short*)(ws + 56412672);  // 524288 -> 56936960
    unsigned short* h1B    = (unsigned short*)(ws + 56936960);  // 30801920 -> 87738880
    unsigned short* WpH    = (unsigned short*)(ws + 87738880);  // 1132880 (fp16 W k-major)
    float*          Rpad   = (float*)(ws + 89778064);    // 480000 -> 90258064

    // 6 graph nodes: prep(+zeros), part, momcon(+csr), gemm1, gemm2, finish
    k_prep   <<<(PREP_TOT + 255) / 256, 256, 0, stream>>>(Wr, R, w1, w2, WpH, Rpad,
                                                          w1T, w2T, gcur, out);
    k_part   <<<256, 256, 0, stream>>>(idx, Z, gcur, part);
    k_momcon <<<(NA + 63) / 64, 512, 0, stream>>>(Rpad, Z, WpH, gcur, part, gmB);

    k_mfma<KP1, 1><<<960, 256, 0, stream>>>(gmB, w1T, b1, nullptr, (void*)h1B);
    k_mfma<NU,  2><<<960, 256, 0, stream>>>(w2T, h1B, b2, w3, (void*)out);

    k_finish<<<(NA + 255) / 256, 256, 0, stream>>>(out, b3, Z, scale, shift);
}